// Round 10
// baseline (172.654 us; speedup 1.0000x reference)
//
#include <hip/hip_runtime.h>

typedef __attribute__((ext_vector_type(8))) short short8;
typedef __attribute__((ext_vector_type(4))) float f32x4;

#define MFMA_BF16 __builtin_amdgcn_mfma_f32_16x16x32_bf16

__device__ __forceinline__ unsigned short f2bf(float f) {
  unsigned u = __builtin_bit_cast(unsigned, f);
  u += 0x7fffu + ((u >> 16) & 1u);
  return (unsigned short)(u >> 16);
}

__device__ __forceinline__ unsigned cvtpk(float a, float b) {  // lo=bf16(a), hi=bf16(b)
  unsigned r;
  asm("v_cvt_pk_bf16_f32 %0, %1, %2" : "=v"(r) : "v"(a), "v"(b));
  return r;
}

// ---------------- fused fp32 -> bf16 convert for all 5 inputs ----------------
__global__ __launch_bounds__(256) void f2b5_kernel(const float* __restrict__ x,
                                                   const float* __restrict__ wq,
                                                   const float* __restrict__ wk,
                                                   const float* __restrict__ wv,
                                                   const float* __restrict__ wo,
                                                   unsigned short* __restrict__ xb,
                                                   unsigned short* __restrict__ wb,
                                                   unsigned short* __restrict__ wob) {
  const int b = blockIdx.x;
  const float* src;
  unsigned short* dst;
  int base;
  if (b < 4096)      { src = x;  dst = xb;                base = b; }
  else if (b < 8192) { src = wq; dst = wb;                base = b - 4096; }
  else if (b < 9216) { src = wk; dst = wb + 2048 * 2048;  base = b - 8192; }
  else if (b < 10240){ src = wv; dst = wb + 2560 * 2048;  base = b - 9216; }
  else               { src = wo; dst = wob;               base = b - 10240; }
  const int i = base * 256 + threadIdx.x;
  const float4 v = ((const float4*)src)[i];
  ushort4 o = make_ushort4(f2bf(v.x), f2bf(v.y), f2bf(v.z), f2bf(v.w));
  ((ushort4*)dst)[i] = o;
}

// ---------------- RoPE trig table: [N][32] cos/sin (f64 once, tiny) ----------------
__global__ __launch_bounds__(256) void trig_kernel(float* __restrict__ cosT, float* __restrict__ sinT) {
  int i = blockIdx.x * 256 + threadIdx.x;  // [0, 2048*32)
  int n = i >> 5, f = i & 31;
  double ang = (double)n * pow(10000.0, -(double)f / 32.0);
  cosT[i] = (float)cos(ang);
  sinT[i] = (float)sin(ang);
}

// ---------------- split-K partial reduce: out = a + b (float4 x2 per thread) ----------------
__global__ __launch_bounds__(256) void add2_kernel(const float* __restrict__ a,
                                                   const float* __restrict__ b,
                                                   float* __restrict__ o) {
  int i = blockIdx.x * 256 + threadIdx.x;
#pragma unroll
  for (int s = 0; s < 2; ++s) {
    const float4 u = ((const float4*)a)[i], v = ((const float4*)b)[i];
    ((float4*)o)[i] = make_float4(u.x + v.x, u.y + v.y, u.z + v.z, u.w + v.w);
    i += 524288;
  }
}

// ---------------- bf16 NT GEMM, 2-phase double-buffered, split-K to partials ----------------
// C_z[M][N] = A[M][Kchunk_z] * B[N][Kchunk_z]^T ; z-slice writes C + z*M*N (plain stores).
// LDS chunk-XOR swizzle: LDS chunk c of row r holds global chunk c^(r&3)  (pre-swizzled src).
__global__ __launch_bounds__(256) void gemm_bt(const short* __restrict__ A,
                                               const short* __restrict__ B,
                                               float* __restrict__ C,
                                               int M, int N, int K, int KC) {
  __shared__ __align__(16) short As[2][128 * 32];
  __shared__ __align__(16) short Bs[2][128 * 32];
  const int tid = threadIdx.x;
  const int w = tid >> 6, lane = tid & 63;
  const int fr = lane & 15, fs = lane >> 4;
  const size_t brow = (size_t)blockIdx.y * 128, bcol = (size_t)blockIdx.x * 128;
  const int wr = (w >> 1) * 64, wc = (w & 1) * 64;
  const int lr = tid >> 2;          // staging row 0..63 (+64 for 2nd issue)
  const int lcS = ((tid & 3) ^ (lr & 3)) * 8;  // pre-swizzled source chunk (8 bf16 = 16B)
  const int ks = blockIdx.z * KC;
  C += (size_t)blockIdx.z * ((size_t)M * N);   // partial buffer for this z-slice
  const short* ga = A + (brow + lr) * (size_t)K + lcS + ks;
  const short* gb = B + (bcol + lr) * (size_t)K + lcS + ks;
  f32x4 acc[4][4] = {};

  auto stage = [&](int sb, int k0) {
    short* lA = As[sb] + w * 512;   // wave-uniform LDS dest (HW: base + lane*16B)
    short* lB = Bs[sb] + w * 512;
    __builtin_amdgcn_global_load_lds((__attribute__((address_space(1))) void*)(ga + k0),
                                     (__attribute__((address_space(3))) void*)(lA), 16, 0, 0);
    __builtin_amdgcn_global_load_lds((__attribute__((address_space(1))) void*)(ga + (size_t)64 * K + k0),
                                     (__attribute__((address_space(3))) void*)(lA + 2048), 16, 0, 0);
    __builtin_amdgcn_global_load_lds((__attribute__((address_space(1))) void*)(gb + k0),
                                     (__attribute__((address_space(3))) void*)(lB), 16, 0, 0);
    __builtin_amdgcn_global_load_lds((__attribute__((address_space(1))) void*)(gb + (size_t)64 * K + k0),
                                     (__attribute__((address_space(3))) void*)(lB + 2048), 16, 0, 0);
  };

  const int nk = KC >> 5;
  stage(0, 0);
  __syncthreads();                  // drain prologue loads
  int buf = 0;
  for (int t = 0; t < nk; ++t) {
    if (t + 1 < nk) stage(buf ^ 1, (t + 1) * 32);  // issue next-tile loads (in flight over MFMA)
    short8 af[4], bfr[4];
#pragma unroll
    for (int m = 0; m < 4; ++m)
      af[m] = *(const short8*)(As[buf] + (wr + m * 16 + fr) * 32 + ((fs ^ (fr & 3)) * 8));
#pragma unroll
    for (int n = 0; n < 4; ++n)
      bfr[n] = *(const short8*)(Bs[buf] + (wc + n * 16 + fr) * 32 + ((fs ^ (fr & 3)) * 8));
#pragma unroll
    for (int m = 0; m < 4; ++m)
#pragma unroll
      for (int n = 0; n < 4; ++n)
        acc[m][n] = MFMA_BF16(af[m], bfr[n], acc[m][n], 0, 0, 0);
    __syncthreads();                // vmcnt(0)+barrier: next tile staged, this buf free
    buf ^= 1;
  }
#pragma unroll
  for (int m = 0; m < 4; ++m)
#pragma unroll
    for (int n = 0; n < 4; ++n)
#pragma unroll
      for (int j = 0; j < 4; ++j)
        C[(brow + wr + m * 16 + fs * 4 + j) * (size_t)N + bcol + wc + n * 16 + fr] = acc[m][n][j];
}

// ---------------- fused split-K reduce + QK-RMSNorm + RoPE + head-major scatter ----------------
// qkv partials: qkvA/qkvB [N][3072] fp32 (q 0:2048 | k 2048:2560 | v 2560:3072); row = A + B
// qb: [H][N][64] bf16 (Q pre-scaled by D^-0.5 * log2e) ; kb: [KV][N][64] ; vbt: [KV][64][N]
__global__ __launch_bounds__(256) void prep_kernel(const float* __restrict__ qkv,
                                                   const float* __restrict__ qw,
                                                   const float* __restrict__ kw,
                                                   const float* __restrict__ cosT,
                                                   const float* __restrict__ sinT,
                                                   short* __restrict__ qb,
                                                   short* __restrict__ kb,
                                                   short* __restrict__ vbt) {
  const int n = blockIdx.x, t = threadIdx.x;
  const int w = t >> 6, lane = t & 63;
  __shared__ float redq[4], redk[4];
  const float* rowA = qkv + (size_t)n * 3072;
  const float* rowB = rowA + 6291456;  // second z-partial
  const float* cT = cosT + n * 32;
  const float* sT = sinT + n * 32;
  // --- Q: 2048 elems, 8/thread, norm over full 2048 ---
  const float4* r4a = (const float4*)rowA;
  const float4* r4b = (const float4*)rowB;
  float4 a0 = r4a[t * 2], a1 = r4b[t * 2];
  float4 b0 = r4a[t * 2 + 1], b1 = r4b[t * 2 + 1];
  float4 a = make_float4(a0.x + a1.x, a0.y + a1.y, a0.z + a1.z, a0.w + a1.w);
  float4 b = make_float4(b0.x + b1.x, b0.y + b1.y, b0.z + b1.z, b0.w + b1.w);
  float ss = a.x*a.x + a.y*a.y + a.z*a.z + a.w*a.w + b.x*b.x + b.y*b.y + b.z*b.z + b.w*b.w;
#pragma unroll
  for (int off = 32; off > 0; off >>= 1) ss += __shfl_xor(ss, off);
  if (lane == 0) redq[w] = ss;
  __syncthreads();
  // fold D^-0.5 and log2(e) (scores in log2-domain for exp2-based softmax)
  float rsq = rsqrtf((redq[0] + redq[1] + redq[2] + redq[3]) * (1.0f / 2048.f) + 1e-6f)
              * 0.125f * 1.44269504088896f;
  const int base = t * 8;
  float y[8] = {a.x, a.y, a.z, a.w, b.x, b.y, b.z, b.w};
#pragma unroll
  for (int e = 0; e < 8; ++e) y[e] *= rsq * qw[base + e];
  short8 ov;
  const int dbase = base & 63;
#pragma unroll
  for (int p = 0; p < 4; ++p) {
    float c = cT[(dbase >> 1) + p], s = sT[(dbase >> 1) + p];
    float x1 = y[2 * p], x2 = y[2 * p + 1];
    ov[2 * p]     = (short)f2bf(x1 * c - x2 * s);
    ov[2 * p + 1] = (short)f2bf(x1 * s + x2 * c);
  }
  const int h = base >> 6;
  *(short8*)(qb + ((size_t)h * 2048 + n) * 64 + dbase) = ov;
  // --- K: 512 elems, 2/thread, norm over full 512 ---
  const int ki = t * 2;
  float2 k0 = *(const float2*)(rowA + 2048 + ki);
  float2 k1 = *(const float2*)(rowB + 2048 + ki);
  float2 kv2 = make_float2(k0.x + k1.x, k0.y + k1.y);
  float ssk = kv2.x * kv2.x + kv2.y * kv2.y;
#pragma unroll
  for (int off = 32; off > 0; off >>= 1) ssk += __shfl_xor(ssk, off);
  if (lane == 0) redk[w] = ssk;
  __syncthreads();
  float rsk = rsqrtf((redk[0] + redk[1] + redk[2] + redk[3]) * (1.0f / 512.f) + 1e-6f);
  float z0 = kv2.x * rsk * kw[ki], z1 = kv2.y * rsk * kw[ki + 1];
  const int kd = ki & 63, kvh = ki >> 6;
  {
    float c = cT[kd >> 1], s = sT[kd >> 1];
    ushort2 o2 = make_ushort2(f2bf(z0 * c - z1 * s), f2bf(z0 * s + z1 * c));
    *(ushort2*)(kb + ((size_t)kvh * 2048 + n) * 64 + kd) = o2;
  }
  // --- V: bf16 + transpose store [KV][64][N] ---
  float2 v0 = *(const float2*)(rowA + 2560 + ki);
  float2 v1 = *(const float2*)(rowB + 2560 + ki);
  vbt[((size_t)kvh * 64 + kd) * 2048 + n]       = (short)f2bf(v0.x + v1.x);
  vbt[((size_t)kvh * 64 + kd + 1) * 2048 + n]   = (short)f2bf(v0.y + v1.y);
}

// ---------------- causal GQA flash attention v8: 32 q-rows/wave ----------------
// 512 blocks; block = (head, 128 q-rows) = 4 waves * 32 rows (2 m-groups of 16).
// K/V LDS reads amortized over both m-groups (per-work LDS ops 22 -> 14).
// Grid mapping idx<8 ? 15-idx : idx-8 pairs qblk q with 15-q on the same CU under
// round-robin dispatch (2 blocks/CU co-resident, tile-work/CU ~ constant 34).
// Swapped MFMA(K,Q) softmax core from v7 (scalar m/l per lane, cvt_pk, b64 P-writes).
__global__ __launch_bounds__(256, 2) void attn_kernel(const short* __restrict__ qb,
                                                      const short* __restrict__ kb,
                                                      const short* __restrict__ vbt,
                                                      short* __restrict__ ab) {
  const int bid = blockIdx.x;
  const int h = bid & 31;
  const int idx = bid >> 5;               // 0..15
  const int qblk = idx < 8 ? 15 - idx : idx - 8;  // big blocks dispatch first
  const int kvh = h >> 2;                 // G=4
  const int tid = threadIdx.x;
  const int w = tid >> 6, lane = tid & 63;
  const int fr = lane & 15, fs = lane >> 4;
  const int q0w = qblk * 128 + w * 32;    // this wave's first q row (32 rows)
  __shared__ __align__(16) short Ks[2][64][64];  // [buf][kv][d], chunk c holds global chunk c^(kv&7)
  __shared__ __align__(16) short Vs[2][64][64];  // [buf][d][kv], chunk c holds global chunk c^(d&7)
  __shared__ __align__(16) short Ps[4][2][16][64];  // per-wave per-group P, u64-slot swizzled
  const short* Kb = kb + (size_t)kvh * 2048 * 64;
  const short* Vb = vbt + (size_t)kvh * 64 * 2048;
  // Q fragments (B-operand): lane fr <-> q row within group m
  short8 qf[2][2];
#pragma unroll
  for (int m = 0; m < 2; ++m) {
    const short* qrow = qb + ((size_t)h * 2048 + q0w + m * 16 + fr) * 64;
    qf[m][0] = *(const short8*)(qrow + fs * 8);
    qf[m][1] = *(const short8*)(qrow + 32 + fs * 8);
  }
  short8 ones8;
#pragma unroll
  for (int e = 0; e < 8; ++e) ones8[e] = (short)0x3F80;  // bf16 1.0
  f32x4 accO[2][4] = {};                  // O^T per group
  f32x4 lacc[2] = {};
  float mrun[2] = {-1e30f, -1e30f};       // scalar running max per group (lane q row)
  const int swz = (fr & 7) << 1;          // u64-slot XOR

  const int rS = lane >> 3;               // staging row within 8-row strip
  const int cS = (lane & 7) ^ rS;         // pre-swizzled source chunk
  auto stage = [&](int sb, int kv0s) {
#pragma unroll
    for (int i = 0; i < 2; ++i) {
      int r = i * 32 + w * 8 + rS;        // r & 7 == rS
      __builtin_amdgcn_global_load_lds(
          (__attribute__((address_space(1))) void*)(Kb + (size_t)(kv0s + r) * 64 + cS * 8),
          (__attribute__((address_space(3))) void*)(&Ks[sb][0][0] + i * 2048 + w * 512), 16, 0, 0);
      __builtin_amdgcn_global_load_lds(
          (__attribute__((address_space(1))) void*)(Vb + (size_t)r * 2048 + kv0s + cS * 8),
          (__attribute__((address_space(3))) void*)(&Vs[sb][0][0] + i * 2048 + w * 512), 16, 0, 0);
    }
  };

  const int ntiles = qblk * 2 + 2;
  int buf = 0;
  stage(0, 0);
  __syncthreads();
  for (int t = 0; t < ntiles; ++t) {
    const int kv0 = t * 64;
    if (t + 1 < ntiles) stage(buf ^ 1, (t + 1) * 64);
    if (kv0 <= q0w + 31) {                // wave-uniform: skip fully-masked tiles
      const short* KsB = &Ks[buf][0][0];
      const short* VsB = &Vs[buf][0][0];
      const int sw = (fr & 7);
      // ---- QK^T swapped, both groups share K fragments ----
      f32x4 sc[2][4];
#pragma unroll
      for (int ct = 0; ct < 4; ++ct) {
        const int rk = ct * 16 + fr;
        short8 kf0 = *(const short8*)(KsB + rk * 64 + ((fs ^ sw) * 8));
        short8 kf1 = *(const short8*)(KsB + rk * 64 + (((4 + fs) ^ sw) * 8));
#pragma unroll
        for (int m = 0; m < 2; ++m) {
          f32x4 a = {};
          a = MFMA_BF16(kf0, qf[m][0], a, 0, 0, 0);
          a = MFMA_BF16(kf1, qf[m][1], a, 0, 0, 0);
          sc[m][ct] = a;
        }
      }
      // ---- causal mask (boundary tiles per group): kv > q ----
#pragma unroll
      for (int m = 0; m < 2; ++m) {
        const int qm = q0w + m * 16 + fr;
        if (kv0 + 63 > qm - fr) {         // group boundary check (wave-uniform-ish, cheap)
#pragma unroll
          for (int ct = 0; ct < 4; ++ct) {
            const int kvb = kv0 + ct * 16 + fs * 4;
#pragma unroll
            for (int j = 0; j < 4; ++j)
              if (kvb + j > qm) sc[m][ct][j] = -1e30f;
          }
        }
      }
      // ---- softmax per group: 15 fmax + 2 shfl, defer-max, exp2, cvt_pk, b64 writes ----
#pragma unroll
      for (int m = 0; m < 2; ++m) {
        float v0m = fmaxf(fmaxf(sc[m][0][0], sc[m][0][1]), fmaxf(sc[m][0][2], sc[m][0][3]));
        float v1m = fmaxf(fmaxf(sc[m][1][0], sc[m][1][1]), fmaxf(sc[m][1][2], sc[m][1][3]));
        float v2m = fmaxf(fmaxf(sc[m][2][0], sc[m][2][1]), fmaxf(sc[m][2][2], sc[m][2][3]));
        float v3m = fmaxf(fmaxf(sc[m][3][0], sc[m][3][1]), fmaxf(sc[m][3][2], sc[m][3][3]));
        float vmax = fmaxf(fmaxf(v0m, v1m), fmaxf(v2m, v3m));
        vmax = fmaxf(vmax, __shfl_xor(vmax, 16));
        vmax = fmaxf(vmax, __shfl_xor(vmax, 32));
        if (!__all(vmax - mrun[m] <= 8.0f)) {
          float mn = fmaxf(mrun[m], vmax);
          float resc = exp2f(mrun[m] - mn);
          mrun[m] = mn;
          lacc[m] *= resc;
#pragma unroll
          for (int dt = 0; dt < 4; ++dt)
#pragma unroll
            for (int j = 0; j < 4; ++j) accO[m][dt][j] *= resc;
        }
        short* prow = &Ps[w][m][fr][0];
#pragma unroll
        for (int ct = 0; ct < 4; ++ct) {
          uint2 pk;
          pk.x = cvtpk(exp2f(sc[m][ct][0] - mrun[m]), exp2f(sc[m][ct][1] - mrun[m]));
          pk.y = cvtpk(exp2f(sc[m][ct][2] - mrun[m]), exp2f(sc[m][ct][3] - mrun[m]));
          *(uint2*)(prow + (((ct * 4 + fs) ^ swz) * 4)) = pk;
        }
      }
      // ---- PV + row-sum, both groups share V fragments ----
      short8 pa[2][2];
#pragma unroll
      for (int m = 0; m < 2; ++m) {
        short* prow = &Ps[w][m][fr][0];
#pragma unroll
        for (int s = 0; s < 2; ++s)
          pa[m][s] = *(const short8*)(prow + (((s * 8 + fs * 2) ^ swz) * 4));
      }
      __builtin_amdgcn_s_setprio(1);
#pragma unroll
      for (int m = 0; m < 2; ++m) {
        lacc[m] = MFMA_BF16(ones8, pa[m][0], lacc[m], 0, 0, 0);
        lacc[m] = MFMA_BF16(ones8, pa[m][1], lacc[m], 0, 0, 0);
      }
#pragma unroll
      for (int dt = 0; dt < 4; ++dt) {
        const int rv = dt * 16 + fr;
        short8 vf0 = *(const short8*)(VsB + rv * 64 + ((fs ^ sw) * 8));
        short8 vf1 = *(const short8*)(VsB + rv * 64 + (((4 + fs) ^ sw) * 8));
#pragma unroll
        for (int m = 0; m < 2; ++m) {
          accO[m][dt] = MFMA_BF16(vf0, pa[m][0], accO[m][dt], 0, 0, 0);
          accO[m][dt] = MFMA_BF16(vf1, pa[m][1], accO[m][dt], 0, 0, 0);
        }
      }
      __builtin_amdgcn_s_setprio(0);
    }
    __syncthreads();
    buf ^= 1;
  }
  // ---- epilogue: O = O^T normalized; packed 8B stores per group ----
#pragma unroll
  for (int m = 0; m < 2; ++m) {
    const float inv = 1.0f / lacc[m][0];
    short* orow = ab + (size_t)(q0w + m * 16 + fr) * 2048 + h * 64;
#pragma unroll
    for (int dt = 0; dt < 4; ++dt) {
      uint2 o;
      o.x = cvtpk(accO[m][dt][0] * inv, accO[m][dt][1] * inv);
      o.y = cvtpk(accO[m][dt][2] * inv, accO[m][dt][3] * inv);
      *(uint2*)(orow + dt * 16 + fs * 4) = o;
    }
  }
}

extern "C" void kernel_launch(void* const* d_in, const int* in_sizes, int n_in,
                              void* d_out, int out_size, void* d_ws, size_t ws_size,
                              hipStream_t stream) {
  const float* x  = (const float*)d_in[0];
  const float* wq = (const float*)d_in[1];
  const float* wk = (const float*)d_in[2];
  const float* wv = (const float*)d_in[3];
  const float* wo = (const float*)d_in[4];
  const float* qw = (const float*)d_in[5];
  const float* kw = (const float*)d_in[6];
  float* out = (float*)d_out;
  char* ws = (char*)d_ws;
  short* xb    = (short*)(ws + 0);          // 8 MB  : x bf16, then attn-out bf16
  short* wb    = (short*)(ws + 8388608);    // 12 MB : [wq;wk;wv] bf16 [3072][2048]
  short* wob   = (short*)(ws + 20971520);   // 8 MB  : wo bf16
  float* qkvfA = (float*)(ws + 29360128);   // 24 MB : qkv z0 partial [2048][3072] f32
  float* qkvfB = (float*)(ws + 54525952);   // 24 MB : qkv z1 partial (contiguous after A)
  short* qb    = (short*)(ws + 79691776);   // 8 MB  : q roped+scaled [32][2048][64]
  short* kb    = (short*)(ws + 88080384);   // 2 MB  : k roped [8][2048][64]
  short* vbt   = (short*)(ws + 90177536);   // 2 MB  : v^T [8][64][2048]
  float* cosT  = (float*)(ws + 92274688);   // 256 KB
  float* sinT  = (float*)(ws + 92536832);   // 256 KB  (total ~88.5 MB)
  short* ab = xb;
  // GEMM2 partials reuse the dead qkvf region after prep (2 x 16 MB <= 48 MB)
  float* po0 = qkvfA;
  float* po1 = qkvfA + 4194304;
  (void)qkvfB; (void)ws_size;

  f2b5_kernel<<<14336, 256, 0, stream>>>(x, wq, wk, wv, wo,
                                         (unsigned short*)xb, (unsigned short*)wb,
                                         (unsigned short*)wob);
  trig_kernel<<<256, 256, 0, stream>>>(cosT, sinT);
  gemm_bt<<<dim3(24, 16, 2), 256, 0, stream>>>(xb, wb, qkvfA, 2048, 3072, 2048, 1024);
  prep_kernel<<<2048, 256, 0, stream>>>(qkvfA, qw, kw, cosT, sinT, qb, kb, vbt);
  attn_kernel<<<512, 256, 0, stream>>>(qb, kb, vbt, ab);
  gemm_bt<<<dim3(16, 16, 2), 256, 0, stream>>>(ab, wob, po0, 2048, 2048, 2048, 1024);
  add2_kernel<<<2048, 256, 0, stream>>>(po0, po1, out);
}